// Round 5
// baseline (214.115 us; speedup 1.0000x reference)
//
#include <hip/hip_runtime.h>
#include <hip/hip_bf16.h>

// Problem constants (from reference)
constexpr int BATCH = 4096;   // N
constexpr int NCLS  = 751;    // classes
constexpr int FDIM  = 2048;   // D
constexpr int TILE  = 128;    // C-tile (square)
constexpr int BK    = 64;     // K-step per phase (2x mfma_16x16x32_fp8 sub-chunks)
constexpr int PH    = FDIM / BK;  // 32 phases
constexpr float MARGIN = 0.5f;

constexpr int NTILE = BATCH / TILE;               // 32
constexpr int NOFF  = NTILE * (NTILE - 1) / 2;    // 496 strictly-lower tiles
constexpr int NGEMM = NOFF + NTILE;               // 528 (diag tiles last)
constexpr int NXENT = 512;                        // xent blocks, 8 rows each
constexpr int NBLK  = NGEMM + NXENT;              // 1040 total mega blocks

typedef __attribute__((ext_vector_type(4))) float f32x4;
typedef __attribute__((ext_vector_type(2))) long long i64x2;  // one ds_read_b128

// ---------------- helpers ----------------
__device__ __forceinline__ float wave_sum(float v) {
#pragma unroll
  for (int m = 32; m >= 1; m >>= 1) v += __shfl_xor(v, m, 64);
  return v;
}

__device__ __forceinline__ void gld_lds16(const void* g, void* l) {
  __builtin_amdgcn_global_load_lds(
      (const __attribute__((address_space(1))) void*)g,
      (__attribute__((address_space(3))) void*)l, 16, 0, 0);
}

// ---------------- kernel 1: fp32->fp8(e4m3) convert (k-PERMUTED) + sq ----
// fb stores a column-permuted copy: within each 64-byte k-group, source byte
// k = ks*32 + quad*8 + b lands at dest byte quad*16 + ks*8 + b. The Gram MFMA
// sums over k with BOTH operands read from fb in the same order, so any global
// column permutation leaves G exactly unchanged. This makes each lane's two
// sub-chunk fragments 16 CONTIGUOUS bytes -> single ds_read_b128 (the round-1
// pattern that measured 0 bank conflicts), vs ds_read_b64 (8192 cyc/block).
// sq is computed from the ORIGINAL fp32 values.
__global__ void convert_init_kernel(const float* __restrict__ feat,
                                    unsigned char* __restrict__ fb,
                                    float* __restrict__ sq,
                                    int* __restrict__ an, int* __restrict__ ap,
                                    int* __restrict__ done) {
  const int row = blockIdx.x;
  const int tid = threadIdx.x;
  const float4* src = (const float4*)(feat + (size_t)row * FDIM);
  uint2* dst = (uint2*)(fb + (size_t)row * FDIM);

  // thread t handles source k in [8t, 8t+8): group g = t>>3, ks = (t&7)>>2,
  // quad = t&3 -> dest 8-byte slot index g*8 + quad*2 + ks.
  const float4 v0 = src[2 * tid];
  const float4 v1 = src[2 * tid + 1];
  float s = v0.x * v0.x + v0.y * v0.y + v0.z * v0.z + v0.w * v0.w +
            v1.x * v1.x + v1.y * v1.y + v1.z * v1.z + v1.w * v1.w;
  int p0 = __builtin_amdgcn_cvt_pk_fp8_f32(v0.x, v0.y, 0, false);
  p0 = __builtin_amdgcn_cvt_pk_fp8_f32(v0.z, v0.w, p0, true);
  int p1 = __builtin_amdgcn_cvt_pk_fp8_f32(v1.x, v1.y, 0, false);
  p1 = __builtin_amdgcn_cvt_pk_fp8_f32(v1.z, v1.w, p1, true);
  uint2 o = {(unsigned)p0, (unsigned)p1};
  dst[(tid >> 3) * 8 + (tid & 3) * 2 + ((tid & 7) >> 2)] = o;

  s = wave_sum(s);
  __shared__ float ss[4];
  if ((tid & 63) == 0) ss[tid >> 6] = s;
  __syncthreads();
  if (tid == 0) {
    sq[row] = ss[0] + ss[1] + ss[2] + ss[3];
    an[row] = 0x7F000000;   // large positive float bits (min identity)
    ap[row] = 0;            // 0.0f bits (max identity; dist >= 0)
    if (row == 0) *done = 0;   // completion counter for the fused finish
  }
}

// ---------------- kernel 2 (mega): heterogeneous blocks + fused finish ----
// blocks [0, NGEMM): fp8 MFMA Gram tile + fused batch-hard mining.
//   BK=64 phases (32 barriers); triple-buffered counted-vmcnt pipeline
//   (vmcnt(4), depth-2) + 16B-slot XOR swizzle on BOTH sides; fragment reads
//   are single ds_read_b128 thanks to the k-permuted fb layout.
// blocks [NGEMM, NBLK): cross-entropy, 8 rows per block (1 row/wave x2).
// Tail: fence + done-counter; the LAST block to finish reduces an/ap/xloss
//   into out (removes the separate final kernel; no spin -> no deadlock).
__global__ __launch_bounds__(256, 3) void mega_kernel(
    const unsigned char* __restrict__ fb, const float* __restrict__ sq,
    int* __restrict__ an, int* __restrict__ ap,
    const float* __restrict__ logits, const int* __restrict__ tgt,
    float* __restrict__ xloss, int* __restrict__ done,
    float* __restrict__ out) {
  const int b = blockIdx.x;
  const int tid = threadIdx.x;
  const int wave = tid >> 6, lane = tid & 63;

  if (b >= NGEMM) {
    // ---------------- cross-entropy part ----------------
    const int r0 = (b - NGEMM) * 8;
#pragma unroll
    for (int rr = 0; rr < 2; ++rr) {
      const int row = r0 + rr * 4 + wave;
      const float* lg = logits + (size_t)row * NCLS;
      float m = -1e30f;
      for (int j = lane; j < NCLS; j += 64) m = fmaxf(m, lg[j]);
#pragma unroll
      for (int s = 32; s >= 1; s >>= 1) m = fmaxf(m, __shfl_xor(m, s, 64));
      float se = 0.f;
      for (int j = lane; j < NCLS; j += 64) se += __expf(lg[j] - m);
      se = wave_sum(se);
      if (lane == 0) xloss[row] = -(lg[tgt[row]] - m - logf(se));
    }
  } else {
    // ---------------- GEMM + mining part ----------------
    __shared__ __align__(16) unsigned char As[3][TILE * BK];  // 3 x 8 KB
    __shared__ __align__(16) unsigned char Bs[3][TILE * BK];  // 3 x 8 KB

    int bi, bj;
    bool diag;
    if (b < NOFF) {
      // strictly-lower triangle: b = bi*(bi-1)/2 + bj, bj < bi
      bi = (int)((1.f + sqrtf(8.f * (float)b + 1.f)) * 0.5f);
      while (bi * (bi - 1) / 2 > b) --bi;
      while ((bi + 1) * bi / 2 <= b) ++bi;
      bj = b - bi * (bi - 1) / 2;
      diag = false;
    } else {
      bi = bj = b - NOFF;
      diag = true;
    }

    const int i0 = bi * TILE, j0 = bj * TILE;
    const int wm = wave >> 1, wn = wave & 1;        // 2x2 wave grid
    const int quad = lane >> 4, lr = lane & 15;

    f32x4 acc[4][4];
    const f32x4 zero = {0.f, 0.f, 0.f, 0.f};
#pragma unroll
    for (int mi = 0; mi < 4; ++mi)
#pragma unroll
      for (int ni = 0; ni < 4; ++ni) acc[mi][ni] = zero;

    // staging map: thread t -> LINEAR LDS byte offset (wave-uniform base +
    // lane*16, required by global_load_lds). Rows are 64B; 16B-slot swizzle
    // applied on BOTH sides: global source slot = (t&3) ^ ((t>>3)&3).
    const int r = tid >> 2;                                   // 0..63
    const int csw = (((tid & 3) ^ ((tid >> 3) & 3))) * 16;    // swizzled src byte
    const unsigned char* gA = fb + (size_t)(i0 + r) * FDIM + csw;
    const unsigned char* gB = fb + (size_t)(j0 + r) * FDIM + csw;
    const int lo = r * BK + (tid & 3) * 16;                   // linear LDS dest

    // prologue: stage phase 0 -> buf0, phase 1 -> buf1 (4 loads per stage;
    // diag stages B=A redundantly to keep the vmcnt count uniform at 4).
    gld_lds16(gA, &As[0][lo]);
    gld_lds16(gA + (size_t)64 * FDIM, &As[0][lo + 64 * BK]);
    gld_lds16(gB, &Bs[0][lo]);
    gld_lds16(gB + (size_t)64 * FDIM, &Bs[0][lo + 64 * BK]);
    gld_lds16(gA + BK, &As[1][lo]);
    gld_lds16(gA + BK + (size_t)64 * FDIM, &As[1][lo + 64 * BK]);
    gld_lds16(gB + BK, &Bs[1][lo]);
    gld_lds16(gB + BK + (size_t)64 * FDIM, &Bs[1][lo + 64 * BK]);

    // fragment read: ONE ds_read_b128 per (mi)/(ni): 16B at slot quad (swizzled
    // by rx=(lr>>1)&3). Low 8B = ks0 fragment, high 8B = ks1 (k-permuted fb).
    const int sl = ((quad ^ ((lr >> 1) & 3))) * 16;
    const int arow = wm * 64 + lr, brow = wn * 64 + lr;

    auto compute = [&](int cur) {
      const unsigned char* Asb = As[cur];
      const unsigned char* Bsb = Bs[cur];
      i64x2 a[4], bfr[4];
#pragma unroll
      for (int mi = 0; mi < 4; ++mi)
        a[mi] = *(const i64x2*)&Asb[(arow + mi * 16) * BK + sl];
#pragma unroll
      for (int ni = 0; ni < 4; ++ni)
        bfr[ni] = *(const i64x2*)&Bsb[(brow + ni * 16) * BK + sl];
#pragma unroll
      for (int mi = 0; mi < 4; ++mi)
#pragma unroll
        for (int ni = 0; ni < 4; ++ni)
          acc[mi][ni] = __builtin_amdgcn_mfma_f32_16x16x32_fp8_fp8(
              a[mi].x, bfr[ni].x, acc[mi][ni], 0, 0, 0);
#pragma unroll
      for (int mi = 0; mi < 4; ++mi)
#pragma unroll
        for (int ni = 0; ni < 4; ++ni)
          acc[mi][ni] = __builtin_amdgcn_mfma_f32_16x16x32_fp8_fp8(
              a[mi].y, bfr[ni].y, acc[mi][ni], 0, 0, 0);
    };

    // main loop: wait own stage(ph) done (vmcnt(4) leaves stage(ph+1)'s 4
    // loads in flight), lgkmcnt(0) so no wave passes the barrier with
    // ds_reads of the about-to-be-restaged buffer pending, raw s_barrier,
    // then stage ph+2 into the buffer last read at ph-1.
    int cur = 0;
    for (int ph = 0; ph < PH - 2; ++ph) {
      asm volatile("s_waitcnt vmcnt(4)" ::: "memory");
      asm volatile("s_waitcnt lgkmcnt(0)" ::: "memory");
      __builtin_amdgcn_s_barrier();
      asm volatile("" ::: "memory");
      const int ko = (ph + 2) * BK;
      const int nb = (cur >= 1) ? cur - 1 : 2;      // (cur+2)%3
      gld_lds16(gA + ko, &As[nb][lo]);
      gld_lds16(gA + ko + (size_t)64 * FDIM, &As[nb][lo + 64 * BK]);
      gld_lds16(gB + ko, &Bs[nb][lo]);
      gld_lds16(gB + ko + (size_t)64 * FDIM, &Bs[nb][lo + 64 * BK]);
      compute(cur);
      cur = (cur == 2) ? 0 : cur + 1;
    }
    // ph = PH-2: stage(PH-1) still in flight -> vmcnt(4); nothing new to stage
    asm volatile("s_waitcnt vmcnt(4)" ::: "memory");
    asm volatile("s_waitcnt lgkmcnt(0)" ::: "memory");
    __builtin_amdgcn_s_barrier();
    asm volatile("" ::: "memory");
    compute(cur);
    cur = (cur == 2) ? 0 : cur + 1;
    // ph = PH-1: last stage is the only outstanding one -> drain fully
    asm volatile("s_waitcnt vmcnt(0)" ::: "memory");
    asm volatile("s_waitcnt lgkmcnt(0)" ::: "memory");
    __builtin_amdgcn_s_barrier();
    asm volatile("" ::: "memory");
    compute(cur);

    // ---- epilogue: D layout col = lane&15 (j), row = quad*4 + reg (i) ----
    float sqj[4];
#pragma unroll
    for (int ni = 0; ni < 4; ++ni) sqj[ni] = sq[j0 + wn * 64 + ni * 16 + lr];

    if (diag) {
      // same-group pairs live only here; tile symmetric -> row mining suffices
      float rmin[4][4], rmax[4][4];
#pragma unroll
      for (int mi = 0; mi < 4; ++mi)
#pragma unroll
        for (int rg = 0; rg < 4; ++rg) { rmin[mi][rg] = 1e30f; rmax[mi][rg] = 0.f; }
#pragma unroll
      for (int mi = 0; mi < 4; ++mi) {
#pragma unroll
        for (int rg = 0; rg < 4; ++rg) {
          const int i = i0 + wm * 64 + mi * 16 + quad * 4 + rg;
          const float si = sq[i];
          const int gi = i >> 2;       // targets = idx // 4
#pragma unroll
          for (int ni = 0; ni < 4; ++ni) {
            const int j = j0 + wn * 64 + ni * 16 + lr;
            const float d2 = si + sqj[ni] - 2.f * acc[mi][ni][rg];
            const float dist = sqrtf(fmaxf(d2, 1e-12f));
            if ((j >> 2) == gi) rmax[mi][rg] = fmaxf(rmax[mi][rg], dist);
            else                rmin[mi][rg] = fminf(rmin[mi][rg], dist);
          }
        }
      }
#pragma unroll
      for (int m = 1; m < 16; m <<= 1)
#pragma unroll
        for (int mi = 0; mi < 4; ++mi)
#pragma unroll
          for (int rg = 0; rg < 4; ++rg) {
            rmin[mi][rg] = fminf(rmin[mi][rg], __shfl_xor(rmin[mi][rg], m, 64));
            rmax[mi][rg] = fmaxf(rmax[mi][rg], __shfl_xor(rmax[mi][rg], m, 64));
          }
      if (lr == 0) {
#pragma unroll
        for (int mi = 0; mi < 4; ++mi)
#pragma unroll
          for (int rg = 0; rg < 4; ++rg) {
            const int i = i0 + wm * 64 + mi * 16 + quad * 4 + rg;
            atomicMin(&an[i], __float_as_int(rmin[mi][rg]));
            atomicMax(&ap[i], __float_as_int(rmax[mi][rg]));
          }
      }
    } else {
      // all cross-group: row-min -> an[i], col-min (symmetry) -> an[j]
      float rmin[4][4];
      float cmin[4] = {1e30f, 1e30f, 1e30f, 1e30f};
#pragma unroll
      for (int mi = 0; mi < 4; ++mi)
#pragma unroll
        for (int rg = 0; rg < 4; ++rg) rmin[mi][rg] = 1e30f;
#pragma unroll
      for (int mi = 0; mi < 4; ++mi) {
#pragma unroll
        for (int rg = 0; rg < 4; ++rg) {
          const float si = sq[i0 + wm * 64 + mi * 16 + quad * 4 + rg];
#pragma unroll
          for (int ni = 0; ni < 4; ++ni) {
            const float d2 = si + sqj[ni] - 2.f * acc[mi][ni][rg];
            const float dist = sqrtf(fmaxf(d2, 1e-12f));
            rmin[mi][rg] = fminf(rmin[mi][rg], dist);
            cmin[ni] = fminf(cmin[ni], dist);
          }
        }
      }
      // rows: reduce across lr lanes (masks 1,2,4,8)
#pragma unroll
      for (int m = 1; m < 16; m <<= 1)
#pragma unroll
        for (int mi = 0; mi < 4; ++mi)
#pragma unroll
          for (int rg = 0; rg < 4; ++rg)
            rmin[mi][rg] = fminf(rmin[mi][rg], __shfl_xor(rmin[mi][rg], m, 64));
      if (lr == 0) {
#pragma unroll
        for (int mi = 0; mi < 4; ++mi)
#pragma unroll
          for (int rg = 0; rg < 4; ++rg) {
            const int i = i0 + wm * 64 + mi * 16 + quad * 4 + rg;
            atomicMin(&an[i], __float_as_int(rmin[mi][rg]));
          }
      }
      // cols: reduce across quad groups (masks 16,32)
#pragma unroll
      for (int ni = 0; ni < 4; ++ni) {
        cmin[ni] = fminf(cmin[ni], __shfl_xor(cmin[ni], 16, 64));
        cmin[ni] = fminf(cmin[ni], __shfl_xor(cmin[ni], 32, 64));
      }
      if (quad == 0) {
#pragma unroll
        for (int ni = 0; ni < 4; ++ni) {
          const int j = j0 + wn * 64 + ni * 16 + lr;
          atomicMin(&an[j], __float_as_int(cmin[ni]));
        }
      }
    }
  }

  // ---- fused finish: last block to arrive reduces an/ap/xloss -> out ----
  // Release: every thread fences its own stores (xloss is plain stores), then
  // the block's arrival is published with one device-scope atomicAdd.
  __shared__ int amLast;
  __threadfence();
  __syncthreads();
  if (tid == 0) amLast = (atomicAdd(done, 1) == NBLK - 1);
  __syncthreads();
  if (amLast) {
    __threadfence();   // acquire: invalidate L1 so an/ap/xloss reads are fresh
    float st = 0.f, sx = 0.f;
    for (int i = tid; i < BATCH; i += 256) {
      const float a = __int_as_float(ap[i]);
      const float bn = __int_as_float(an[i]);
      st += fmaxf(a - bn + MARGIN, 0.f);
      sx += xloss[i];
    }
    st = wave_sum(st);
    sx = wave_sum(sx);
    __shared__ float s1[4], s2[4];
    if ((tid & 63) == 0) { s1[tid >> 6] = st; s2[tid >> 6] = sx; }
    __syncthreads();
    if (tid == 0)
      out[0] = (s1[0] + s1[1] + s1[2] + s1[3] +
                s2[0] + s2[1] + s2[2] + s2[3]) / (float)BATCH;  // ALPHA=BETA=1
  }
}

// ---------------- launch ----------------
extern "C" void kernel_launch(void* const* d_in, const int* in_sizes, int n_in,
                              void* d_out, int out_size, void* d_ws, size_t ws_size,
                              hipStream_t stream) {
  const float* logits = (const float*)d_in[0];
  const float* feat   = (const float*)d_in[1];
  const int*   tgt    = (const int*)d_in[2];
  float* out = (float*)d_out;

  // ws layout: fp8 feat copy (8 MB, k-permuted) | sq | an | ap | xloss | done
  char* ws = (char*)d_ws;
  unsigned char* fb = (unsigned char*)ws;
  size_t off = (size_t)BATCH * FDIM * sizeof(unsigned char);
  float* sq    = (float*)(ws + off);  off += BATCH * sizeof(float);
  int*   an    = (int*)(ws + off);    off += BATCH * sizeof(int);
  int*   ap    = (int*)(ws + off);    off += BATCH * sizeof(int);
  float* xloss = (float*)(ws + off);  off += BATCH * sizeof(float);
  int*   done  = (int*)(ws + off);

  convert_init_kernel<<<BATCH, 256, 0, stream>>>(feat, fb, sq, an, ap, done);
  mega_kernel<<<NBLK, 256, 0, stream>>>(fb, sq, an, ap, logits, tgt, xloss,
                                        done, out);
}

// Round 6
// 134.796 us; speedup vs baseline: 1.5884x; 1.5884x over previous
//
#include <hip/hip_runtime.h>
#include <hip/hip_bf16.h>

// Problem constants (from reference)
constexpr int BATCH = 4096;   // N
constexpr int NCLS  = 751;    // classes
constexpr int FDIM  = 2048;   // D
constexpr int TILE  = 128;    // C-tile (square)
constexpr int BK    = 64;     // K-step per phase (2x mfma_16x16x32_fp8 sub-chunks)
constexpr int PH    = FDIM / BK;  // 32 phases
constexpr float MARGIN = 0.5f;

constexpr int NTILE = BATCH / TILE;               // 32
constexpr int NOFF  = NTILE * (NTILE - 1) / 2;    // 496 strictly-lower tiles
constexpr int NGEMM = NOFF + NTILE;               // 528 (diag tiles last)
constexpr int NXENT = 512;                        // xent blocks, 8 rows each

typedef __attribute__((ext_vector_type(4))) float f32x4;
typedef __attribute__((ext_vector_type(2))) long long i64x2;  // one ds_read_b128

// ---------------- helpers ----------------
__device__ __forceinline__ float wave_sum(float v) {
#pragma unroll
  for (int m = 32; m >= 1; m >>= 1) v += __shfl_xor(v, m, 64);
  return v;
}

__device__ __forceinline__ void gld_lds16(const void* g, void* l) {
  __builtin_amdgcn_global_load_lds(
      (const __attribute__((address_space(1))) void*)g,
      (__attribute__((address_space(3))) void*)l, 16, 0, 0);
}

// ---------------- kernel 1: fp32->fp8(e4m3) convert (k-PERMUTED) + sq ----
// fb stores a column-permuted copy: within each 64-byte k-group, source byte
// k = ks*32 + quad*8 + b lands at dest byte quad*16 + ks*8 + b. The Gram MFMA
// sums over k with BOTH operands read from fb in the same order, so a global
// column permutation leaves G exactly unchanged. Each lane's two sub-chunk
// fragments become 16 CONTIGUOUS bytes -> single ds_read_b128 (0 bank
// conflicts, HW-verified round 5) instead of 2x ds_read_b64 (8192 cyc/block).
// sq is computed from the ORIGINAL fp32 values.
__global__ void convert_init_kernel(const float* __restrict__ feat,
                                    unsigned char* __restrict__ fb,
                                    float* __restrict__ sq,
                                    int* __restrict__ an, int* __restrict__ ap) {
  const int row = blockIdx.x;
  const int tid = threadIdx.x;
  const float4* src = (const float4*)(feat + (size_t)row * FDIM);
  uint2* dst = (uint2*)(fb + (size_t)row * FDIM);

  // thread t handles source k in [8t, 8t+8): group g = t>>3, ks = (t&7)>>2,
  // quad = t&3 -> dest 8-byte slot index g*8 + quad*2 + ks.
  const float4 v0 = src[2 * tid];
  const float4 v1 = src[2 * tid + 1];
  float s = v0.x * v0.x + v0.y * v0.y + v0.z * v0.z + v0.w * v0.w +
            v1.x * v1.x + v1.y * v1.y + v1.z * v1.z + v1.w * v1.w;
  int p0 = __builtin_amdgcn_cvt_pk_fp8_f32(v0.x, v0.y, 0, false);
  p0 = __builtin_amdgcn_cvt_pk_fp8_f32(v0.z, v0.w, p0, true);
  int p1 = __builtin_amdgcn_cvt_pk_fp8_f32(v1.x, v1.y, 0, false);
  p1 = __builtin_amdgcn_cvt_pk_fp8_f32(v1.z, v1.w, p1, true);
  uint2 o = {(unsigned)p0, (unsigned)p1};
  dst[(tid >> 3) * 8 + (tid & 3) * 2 + ((tid & 7) >> 2)] = o;

  s = wave_sum(s);
  __shared__ float ss[4];
  if ((tid & 63) == 0) ss[tid >> 6] = s;
  __syncthreads();
  if (tid == 0) {
    sq[row] = ss[0] + ss[1] + ss[2] + ss[3];
    an[row] = 0x7F000000;   // large positive float bits (min identity)
    ap[row] = 0;            // 0.0f bits (max identity; dist >= 0)
  }
}

// ---------------- kernel 2 (mega): heterogeneous blocks ----------------
// blocks [0, NGEMM): fp8 MFMA Gram tile + fused batch-hard mining.
//   BK=64 phases (32 barriers); triple-buffered counted-vmcnt pipeline
//   (vmcnt(4), depth-2) + 16B-slot XOR swizzle on BOTH sides; fragment reads
//   are single ds_read_b128 thanks to the k-permuted fb layout.
// blocks [NGEMM, NGEMM+NXENT): cross-entropy, 8 rows per block (1 row/wave x2).
// NOTE: no per-block device fences here — round 5 showed __threadfence() at
// block-end costs ~88 us chip-wide (L2 writeback/invalidate per block on
// non-coherent XCD L2s). The kernel boundary provides ordering once, cheaply.
__global__ __launch_bounds__(256, 3) void mega_kernel(
    const unsigned char* __restrict__ fb, const float* __restrict__ sq,
    int* __restrict__ an, int* __restrict__ ap,
    const float* __restrict__ logits, const int* __restrict__ tgt,
    float* __restrict__ xloss) {
  const int b = blockIdx.x;
  const int tid = threadIdx.x;
  const int wave = tid >> 6, lane = tid & 63;

  if (b >= NGEMM) {
    // ---------------- cross-entropy part ----------------
    const int r0 = (b - NGEMM) * 8;
#pragma unroll
    for (int rr = 0; rr < 2; ++rr) {
      const int row = r0 + rr * 4 + wave;
      const float* lg = logits + (size_t)row * NCLS;
      float m = -1e30f;
      for (int j = lane; j < NCLS; j += 64) m = fmaxf(m, lg[j]);
#pragma unroll
      for (int s = 32; s >= 1; s >>= 1) m = fmaxf(m, __shfl_xor(m, s, 64));
      float se = 0.f;
      for (int j = lane; j < NCLS; j += 64) se += __expf(lg[j] - m);
      se = wave_sum(se);
      if (lane == 0) xloss[row] = -(lg[tgt[row]] - m - logf(se));
    }
    return;
  }

  // ---------------- GEMM + mining part ----------------
  __shared__ __align__(16) unsigned char As[3][TILE * BK];  // 3 x 8 KB
  __shared__ __align__(16) unsigned char Bs[3][TILE * BK];  // 3 x 8 KB

  int bi, bj;
  bool diag;
  if (b < NOFF) {
    // strictly-lower triangle: b = bi*(bi-1)/2 + bj, bj < bi
    bi = (int)((1.f + sqrtf(8.f * (float)b + 1.f)) * 0.5f);
    while (bi * (bi - 1) / 2 > b) --bi;
    while ((bi + 1) * bi / 2 <= b) ++bi;
    bj = b - bi * (bi - 1) / 2;
    diag = false;
  } else {
    bi = bj = b - NOFF;
    diag = true;
  }

  const int i0 = bi * TILE, j0 = bj * TILE;
  const int wm = wave >> 1, wn = wave & 1;        // 2x2 wave grid
  const int quad = lane >> 4, lr = lane & 15;

  f32x4 acc[4][4];
  const f32x4 zero = {0.f, 0.f, 0.f, 0.f};
#pragma unroll
  for (int mi = 0; mi < 4; ++mi)
#pragma unroll
    for (int ni = 0; ni < 4; ++ni) acc[mi][ni] = zero;

  // staging map: thread t -> LINEAR LDS byte offset (wave-uniform base +
  // lane*16, required by global_load_lds). Rows are 64B; 16B-slot swizzle
  // applied on BOTH sides: global source slot = (t&3) ^ ((t>>3)&3).
  const int r = tid >> 2;                                   // 0..63
  const int csw = (((tid & 3) ^ ((tid >> 3) & 3))) * 16;    // swizzled src byte
  const unsigned char* gA = fb + (size_t)(i0 + r) * FDIM + csw;
  const unsigned char* gB = fb + (size_t)(j0 + r) * FDIM + csw;
  const int lo = r * BK + (tid & 3) * 16;                   // linear LDS dest

  // prologue: stage phase 0 -> buf0, phase 1 -> buf1 (4 loads per stage;
  // diag stages B=A redundantly to keep the vmcnt count uniform at 4).
  gld_lds16(gA, &As[0][lo]);
  gld_lds16(gA + (size_t)64 * FDIM, &As[0][lo + 64 * BK]);
  gld_lds16(gB, &Bs[0][lo]);
  gld_lds16(gB + (size_t)64 * FDIM, &Bs[0][lo + 64 * BK]);
  gld_lds16(gA + BK, &As[1][lo]);
  gld_lds16(gA + BK + (size_t)64 * FDIM, &As[1][lo + 64 * BK]);
  gld_lds16(gB + BK, &Bs[1][lo]);
  gld_lds16(gB + BK + (size_t)64 * FDIM, &Bs[1][lo + 64 * BK]);

  // fragment read: ONE ds_read_b128 per (mi)/(ni): 16B at slot quad (swizzled
  // by rx=(lr>>1)&3). Low 8B = ks0 fragment, high 8B = ks1 (k-permuted fb).
  const int sl = ((quad ^ ((lr >> 1) & 3))) * 16;
  const int arow = wm * 64 + lr, brow = wn * 64 + lr;

  auto compute = [&](int cur) {
    const unsigned char* Asb = As[cur];
    const unsigned char* Bsb = Bs[cur];
    i64x2 a[4], bfr[4];
#pragma unroll
    for (int mi = 0; mi < 4; ++mi)
      a[mi] = *(const i64x2*)&Asb[(arow + mi * 16) * BK + sl];
#pragma unroll
    for (int ni = 0; ni < 4; ++ni)
      bfr[ni] = *(const i64x2*)&Bsb[(brow + ni * 16) * BK + sl];
#pragma unroll
    for (int mi = 0; mi < 4; ++mi)
#pragma unroll
      for (int ni = 0; ni < 4; ++ni)
        acc[mi][ni] = __builtin_amdgcn_mfma_f32_16x16x32_fp8_fp8(
            a[mi].x, bfr[ni].x, acc[mi][ni], 0, 0, 0);
#pragma unroll
    for (int mi = 0; mi < 4; ++mi)
#pragma unroll
      for (int ni = 0; ni < 4; ++ni)
        acc[mi][ni] = __builtin_amdgcn_mfma_f32_16x16x32_fp8_fp8(
            a[mi].y, bfr[ni].y, acc[mi][ni], 0, 0, 0);
  };

  // main loop: wait own stage(ph) done (vmcnt(4) leaves stage(ph+1)'s 4
  // loads in flight), lgkmcnt(0) so no wave passes the barrier with
  // ds_reads of the about-to-be-restaged buffer pending, raw s_barrier,
  // then stage ph+2 into the buffer last read at ph-1.
  int cur = 0;
  for (int ph = 0; ph < PH - 2; ++ph) {
    asm volatile("s_waitcnt vmcnt(4)" ::: "memory");
    asm volatile("s_waitcnt lgkmcnt(0)" ::: "memory");
    __builtin_amdgcn_s_barrier();
    asm volatile("" ::: "memory");
    const int ko = (ph + 2) * BK;
    const int nb = (cur >= 1) ? cur - 1 : 2;      // (cur+2)%3
    gld_lds16(gA + ko, &As[nb][lo]);
    gld_lds16(gA + ko + (size_t)64 * FDIM, &As[nb][lo + 64 * BK]);
    gld_lds16(gB + ko, &Bs[nb][lo]);
    gld_lds16(gB + ko + (size_t)64 * FDIM, &Bs[nb][lo + 64 * BK]);
    compute(cur);
    cur = (cur == 2) ? 0 : cur + 1;
  }
  // ph = PH-2: stage(PH-1) still in flight -> vmcnt(4); nothing new to stage
  asm volatile("s_waitcnt vmcnt(4)" ::: "memory");
  asm volatile("s_waitcnt lgkmcnt(0)" ::: "memory");
  __builtin_amdgcn_s_barrier();
  asm volatile("" ::: "memory");
  compute(cur);
  cur = (cur == 2) ? 0 : cur + 1;
  // ph = PH-1: last stage is the only outstanding one -> drain fully
  asm volatile("s_waitcnt vmcnt(0)" ::: "memory");
  asm volatile("s_waitcnt lgkmcnt(0)" ::: "memory");
  __builtin_amdgcn_s_barrier();
  asm volatile("" ::: "memory");
  compute(cur);

  // ---- epilogue: D layout col = lane&15 (j), row = quad*4 + reg (i) ----
  float sqj[4];
#pragma unroll
  for (int ni = 0; ni < 4; ++ni) sqj[ni] = sq[j0 + wn * 64 + ni * 16 + lr];

  if (diag) {
    // same-group pairs live only here; tile symmetric -> row mining suffices
    float rmin[4][4], rmax[4][4];
#pragma unroll
    for (int mi = 0; mi < 4; ++mi)
#pragma unroll
      for (int rg = 0; rg < 4; ++rg) { rmin[mi][rg] = 1e30f; rmax[mi][rg] = 0.f; }
#pragma unroll
    for (int mi = 0; mi < 4; ++mi) {
#pragma unroll
      for (int rg = 0; rg < 4; ++rg) {
        const int i = i0 + wm * 64 + mi * 16 + quad * 4 + rg;
        const float si = sq[i];
        const int gi = i >> 2;       // targets = idx // 4
#pragma unroll
        for (int ni = 0; ni < 4; ++ni) {
          const int j = j0 + wn * 64 + ni * 16 + lr;
          const float d2 = si + sqj[ni] - 2.f * acc[mi][ni][rg];
          const float dist = sqrtf(fmaxf(d2, 1e-12f));
          if ((j >> 2) == gi) rmax[mi][rg] = fmaxf(rmax[mi][rg], dist);
          else                rmin[mi][rg] = fminf(rmin[mi][rg], dist);
        }
      }
    }
#pragma unroll
    for (int m = 1; m < 16; m <<= 1)
#pragma unroll
      for (int mi = 0; mi < 4; ++mi)
#pragma unroll
        for (int rg = 0; rg < 4; ++rg) {
          rmin[mi][rg] = fminf(rmin[mi][rg], __shfl_xor(rmin[mi][rg], m, 64));
          rmax[mi][rg] = fmaxf(rmax[mi][rg], __shfl_xor(rmax[mi][rg], m, 64));
        }
    if (lr == 0) {
#pragma unroll
      for (int mi = 0; mi < 4; ++mi)
#pragma unroll
        for (int rg = 0; rg < 4; ++rg) {
          const int i = i0 + wm * 64 + mi * 16 + quad * 4 + rg;
          atomicMin(&an[i], __float_as_int(rmin[mi][rg]));
          atomicMax(&ap[i], __float_as_int(rmax[mi][rg]));
        }
    }
  } else {
    // all cross-group: row-min -> an[i], col-min (symmetry) -> an[j]
    float rmin[4][4];
    float cmin[4] = {1e30f, 1e30f, 1e30f, 1e30f};
#pragma unroll
    for (int mi = 0; mi < 4; ++mi)
#pragma unroll
      for (int rg = 0; rg < 4; ++rg) rmin[mi][rg] = 1e30f;
#pragma unroll
    for (int mi = 0; mi < 4; ++mi) {
#pragma unroll
      for (int rg = 0; rg < 4; ++rg) {
        const float si = sq[i0 + wm * 64 + mi * 16 + quad * 4 + rg];
#pragma unroll
        for (int ni = 0; ni < 4; ++ni) {
          const float d2 = si + sqj[ni] - 2.f * acc[mi][ni][rg];
          const float dist = sqrtf(fmaxf(d2, 1e-12f));
          rmin[mi][rg] = fminf(rmin[mi][rg], dist);
          cmin[ni] = fminf(cmin[ni], dist);
        }
      }
    }
    // rows: reduce across lr lanes (masks 1,2,4,8)
#pragma unroll
    for (int m = 1; m < 16; m <<= 1)
#pragma unroll
      for (int mi = 0; mi < 4; ++mi)
#pragma unroll
        for (int rg = 0; rg < 4; ++rg)
          rmin[mi][rg] = fminf(rmin[mi][rg], __shfl_xor(rmin[mi][rg], m, 64));
    if (lr == 0) {
#pragma unroll
      for (int mi = 0; mi < 4; ++mi)
#pragma unroll
        for (int rg = 0; rg < 4; ++rg) {
          const int i = i0 + wm * 64 + mi * 16 + quad * 4 + rg;
          atomicMin(&an[i], __float_as_int(rmin[mi][rg]));
        }
    }
    // cols: reduce across quad groups (masks 16,32)
#pragma unroll
    for (int ni = 0; ni < 4; ++ni) {
      cmin[ni] = fminf(cmin[ni], __shfl_xor(cmin[ni], 16, 64));
      cmin[ni] = fminf(cmin[ni], __shfl_xor(cmin[ni], 32, 64));
    }
    if (quad == 0) {
#pragma unroll
      for (int ni = 0; ni < 4; ++ni) {
        const int j = j0 + wn * 64 + ni * 16 + lr;
        atomicMin(&an[j], __float_as_int(cmin[ni]));
      }
    }
  }
}

// ---------------- kernel 3: final combine ----------------
__global__ void final_kernel(const int* __restrict__ an, const int* __restrict__ ap,
                             const float* __restrict__ xloss, float* __restrict__ out) {
  const int tid = threadIdx.x;
  float st = 0.f, sx = 0.f;
  for (int i = tid; i < BATCH; i += 1024) {
    const float a = __int_as_float(ap[i]);
    const float b = __int_as_float(an[i]);
    st += fmaxf(a - b + MARGIN, 0.f);
    sx += xloss[i];
  }
  st = wave_sum(st);
  sx = wave_sum(sx);
  __shared__ float s1[16], s2[16];
  if ((tid & 63) == 0) { s1[tid >> 6] = st; s2[tid >> 6] = sx; }
  __syncthreads();
  if (tid == 0) {
    float t = 0.f, x = 0.f;
#pragma unroll
    for (int w = 0; w < 16; ++w) { t += s1[w]; x += s2[w]; }
    out[0] = x / (float)BATCH + t / (float)BATCH;  // ALPHA=BETA=1
  }
}

// ---------------- launch ----------------
extern "C" void kernel_launch(void* const* d_in, const int* in_sizes, int n_in,
                              void* d_out, int out_size, void* d_ws, size_t ws_size,
                              hipStream_t stream) {
  const float* logits = (const float*)d_in[0];
  const float* feat   = (const float*)d_in[1];
  const int*   tgt    = (const int*)d_in[2];
  float* out = (float*)d_out;

  // ws layout: fp8 feat copy (8 MB, k-permuted) | sq | an | ap | xloss
  char* ws = (char*)d_ws;
  unsigned char* fb = (unsigned char*)ws;
  size_t off = (size_t)BATCH * FDIM * sizeof(unsigned char);
  float* sq    = (float*)(ws + off);  off += BATCH * sizeof(float);
  int*   an    = (int*)(ws + off);    off += BATCH * sizeof(int);
  int*   ap    = (int*)(ws + off);    off += BATCH * sizeof(int);
  float* xloss = (float*)(ws + off);

  convert_init_kernel<<<BATCH, 256, 0, stream>>>(feat, fb, sq, an, ap);
  mega_kernel<<<NGEMM + NXENT, 256, 0, stream>>>(fb, sq, an, ap, logits, tgt, xloss);
  final_kernel<<<1, 1024, 0, stream>>>(an, ap, xloss, out);
}